// Round 1
// baseline (1603.431 us; speedup 1.0000x reference)
//
#include <hip/hip_runtime.h>
#include <hip/hip_bf16.h>
#include <math.h>

// Problem constants
#define TT 64
#define BB 256      // per-sequence batch
#define BT 512      // total batch (both sequences)
#define DD 300      // embedding dim
#define HH 512      // hidden
#define G4 2048     // 4*H
#define KX 320      // padded x-region of concat-K
#define KTOT 1856   // 320 + 3*512  (x | h_hi | h_lo | h_hi)
#define KC 64       // K chunk per LDS stage
#define NCH 29      // KTOT / KC
#define LDA 72      // LDS row stride in shorts (64 + 8 pad -> 144B rows)

typedef __attribute__((ext_vector_type(8))) short short8v;
typedef __attribute__((ext_vector_type(4))) float f32x4;

__device__ __forceinline__ unsigned short f2bf(float f) {
    union { float f; unsigned int u; } v; v.f = f;
    unsigned int u = v.u;
    u += 0x7fffu + ((u >> 16) & 1u);   // round-to-nearest-even
    return (unsigned short)(u >> 16);
}
__device__ __forceinline__ float bf2f(unsigned short s) {
    union { unsigned int u; float f; } v; v.u = ((unsigned int)s) << 16;
    return v.f;
}
__device__ __forceinline__ float sigm(float x) { return 1.0f / (1.0f + __expf(-x)); }
__device__ __forceinline__ float tanh_f(float x) {
    float ax = fabsf(x);
    if (ax > 15.0f) return (x > 0.0f) ? 1.0f : -1.0f;
    float e = __expf(2.0f * ax);
    float t = 1.0f - 2.0f / (e + 1.0f);
    return (x >= 0.0f) ? t : -t;
}

// ---------------------------------------------------------------------------
// Prep: build Wcat bf16 [2048][1856] = [Wih|pad | Whh_hi | Whh_hi | Whh_lo],
// and bias = b_ih + b_hh.
__global__ __launch_bounds__(256) void prep_w(const float* __restrict__ Wih,
                                              const float* __restrict__ Whh,
                                              const float* __restrict__ bih,
                                              const float* __restrict__ bhh,
                                              unsigned short* __restrict__ Wcat,
                                              float* __restrict__ bias)
{
    const int row = blockIdx.x; // 0..2047
    for (int k = threadIdx.x; k < KTOT; k += 256) {
        unsigned short v;
        if (k < DD)                 v = f2bf(Wih[row * DD + k]);
        else if (k < KX)            v = 0;
        else if (k < KX + HH)       v = f2bf(Whh[row * HH + (k - KX)]);
        else if (k < KX + 2 * HH)   v = f2bf(Whh[row * HH + (k - KX - HH)]);
        else {
            float f = Whh[row * HH + (k - KX - 2 * HH)];
            unsigned short hi = f2bf(f);
            v = f2bf(f - bf2f(hi));
        }
        Wcat[(size_t)row * KTOT + k] = v;
    }
    if (threadIdx.x == 0) bias[row] = bih[row] + bhh[row];
}

// Prep: initial h (hi/lo bf16) and c for both sequences stacked.
__global__ __launch_bounds__(256) void prep_h(const float* __restrict__ h0a,
                                              const float* __restrict__ c0a,
                                              const float* __restrict__ h0b,
                                              const float* __restrict__ c0b,
                                              unsigned short* __restrict__ hhi,
                                              unsigned short* __restrict__ hlo,
                                              float* __restrict__ c)
{
    const int b = blockIdx.x; // 0..511
    for (int j = threadIdx.x; j < HH; j += 256) {
        float hv = (b < BB) ? h0a[b * HH + j] : h0b[(b - BB) * HH + j];
        float cv = (b < BB) ? c0a[b * HH + j] : c0b[(b - BB) * HH + j];
        unsigned short hi = f2bf(hv);
        hhi[b * HH + j] = hi;
        hlo[b * HH + j] = f2bf(hv - bf2f(hi));
        c[b * HH + j] = cv;
    }
}

// ---------------------------------------------------------------------------
// One LSTM timestep for all 512 batch rows.
// Block tile: 64 batch x 64 gate-cols, where the 64 cols = 16 j-columns x 4 gates
// (i,f,g,o) so the cell update can be fused. Grid (8, 32). 4 waves, wave tile 32x32.
__global__ __launch_bounds__(256) void lstm_step(
    const int* __restrict__ s1, const int* __restrict__ s2,
    const float* __restrict__ emb,
    const unsigned short* __restrict__ Wcat,
    const float* __restrict__ bias,
    const unsigned short* __restrict__ hhi_in,
    const unsigned short* __restrict__ hlo_in,
    const float* __restrict__ c_in,
    unsigned short* __restrict__ hhi_out,
    unsigned short* __restrict__ hlo_out,
    float* __restrict__ c_out,
    int t)
{
    __shared__ __align__(16) unsigned short smem[2 * 64 * LDA]; // A then B (18432 B)
    unsigned short* As = smem;
    unsigned short* Bs = smem + 64 * LDA;

    const int tid = threadIdx.x;
    const int bx = blockIdx.x;          // batch block (0..7)
    const int j0 = blockIdx.y * 16;     // hidden-column base

    const int lane = tid & 63;
    const int w = tid >> 6;
    const int wr = w >> 1, wc = w & 1;  // wave tile 32x32 within 64x64
    const int r16 = lane & 15;
    const int kg8 = lane >> 4;

    // staging coordinates: 4 threads per row, each stages 16 shorts (2 x b128)
    const int srow = tid >> 2;                 // 0..63
    const int skk = (tid & 3) * 16;            // 0,16,32,48
    const int sbatch = bx * 64 + srow;
    const int tok = (sbatch < BB) ? s1[t * BB + sbatch] : s2[t * BB + (sbatch - BB)];
    const int scol = (srow >> 4) * HH + j0 + (srow & 15); // Wcat row for B staging

    f32x4 acc[2][2] = {};

    for (int ch = 0; ch < NCH; ++ch) {
        const int k0 = ch * KC;
        __syncthreads();
        #pragma unroll
        for (int gpart = 0; gpart < 2; ++gpart) {
            const int kk = skk + gpart * 8;
            const int kg = k0 + kk;
            // ---- stage A (x | h_hi | h_lo | h_hi) ----
            short8v vals;
            if (kg >= KX) {
                const unsigned short* src;
                if (kg < KX + HH)            src = hhi_in + sbatch * HH + (kg - KX);
                else if (kg < KX + 2 * HH)   src = hlo_in + sbatch * HH + (kg - KX - HH);
                else                         src = hhi_in + sbatch * HH + (kg - KX - 2 * HH);
                vals = *(const short8v*)src;
            } else if (kg + 8 <= DD) {
                const float* e0 = emb + (size_t)tok * DD + kg;
                float4 va = *(const float4*)e0;
                float4 vb = *(const float4*)(e0 + 4);
                vals[0] = (short)f2bf(va.x); vals[1] = (short)f2bf(va.y);
                vals[2] = (short)f2bf(va.z); vals[3] = (short)f2bf(va.w);
                vals[4] = (short)f2bf(vb.x); vals[5] = (short)f2bf(vb.y);
                vals[6] = (short)f2bf(vb.z); vals[7] = (short)f2bf(vb.w);
            } else {
                #pragma unroll
                for (int e = 0; e < 8; ++e) {
                    int cidx = kg + e;
                    vals[e] = (cidx < DD) ? (short)f2bf(emb[(size_t)tok * DD + cidx]) : (short)0;
                }
            }
            *(short8v*)&As[srow * LDA + kk] = vals;
            // ---- stage B (Wcat rows for this block's 64 gate-columns) ----
            *(short8v*)&Bs[srow * LDA + kk] =
                *(const short8v*)(Wcat + (size_t)scol * KTOT + kg);
        }
        __syncthreads();
        #pragma unroll
        for (int ks = 0; ks < KC; ks += 32) {
            const int ko = ks + kg8 * 8;
            short8v a0 = *(const short8v*)&As[(32 * wr + r16) * LDA + ko];
            short8v a1 = *(const short8v*)&As[(32 * wr + 16 + r16) * LDA + ko];
            short8v b0 = *(const short8v*)&Bs[(32 * wc + r16) * LDA + ko];
            short8v b1 = *(const short8v*)&Bs[(32 * wc + 16 + r16) * LDA + ko];
            acc[0][0] = __builtin_amdgcn_mfma_f32_16x16x32_bf16(a0, b0, acc[0][0], 0, 0, 0);
            acc[0][1] = __builtin_amdgcn_mfma_f32_16x16x32_bf16(a0, b1, acc[0][1], 0, 0, 0);
            acc[1][0] = __builtin_amdgcn_mfma_f32_16x16x32_bf16(a1, b0, acc[1][0], 0, 0, 0);
            acc[1][1] = __builtin_amdgcn_mfma_f32_16x16x32_bf16(a1, b1, acc[1][1], 0, 0, 0);
        }
    }

    // exchange gates through LDS so each thread gets (i,f,g,o) for its (b,j)
    __syncthreads();
    float* gbuf = (float*)smem; // 64 x 65 floats (16640 B, fits in 18432)
    #pragma unroll
    for (int i = 0; i < 2; ++i)
        #pragma unroll
        for (int j = 0; j < 2; ++j)
            #pragma unroll
            for (int r = 0; r < 4; ++r) {
                int grow = (2 * wr + i) * 16 + kg8 * 4 + r; // C/D: row=(lane>>4)*4+reg
                int gcol = (2 * wc + j) * 16 + r16;         //      col=lane&15
                gbuf[grow * 65 + gcol] = acc[i][j][r];
            }
    __syncthreads();

    #pragma unroll
    for (int u = 0; u < 4; ++u) {
        int pair = tid + 256 * u;     // 1024 (b,j) pairs
        int row = pair >> 4;
        int jj = pair & 15;
        int batch = bx * 64 + row;
        int j = j0 + jj;
        float gi = gbuf[row * 65 + jj]      + bias[j];
        float gf = gbuf[row * 65 + 16 + jj] + bias[HH + j];
        float gg = gbuf[row * 65 + 32 + jj] + bias[2 * HH + j];
        float go = gbuf[row * 65 + 48 + jj] + bias[3 * HH + j];
        float cp = c_in[batch * HH + j];
        float cn = sigm(gf) * cp + sigm(gi) * tanh_f(gg);
        float hn = sigm(go) * tanh_f(cn);
        c_out[batch * HH + j] = cn;
        unsigned short hi = f2bf(hn);
        hhi_out[batch * HH + j] = hi;
        hlo_out[batch * HH + j] = f2bf(hn - bf2f(hi));
    }
}

// ---------------------------------------------------------------------------
__global__ __launch_bounds__(64) void finalize(const unsigned short* __restrict__ hhi,
                                               const unsigned short* __restrict__ hlo,
                                               float* __restrict__ out)
{
    const int b = blockIdx.x;       // 0..255
    const int lane = threadIdx.x;   // 64
    float s = 0.0f;
    for (int j = lane; j < HH; j += 64) {
        float ha = bf2f(hhi[b * HH + j]) + bf2f(hlo[b * HH + j]);
        float hb = bf2f(hhi[(b + BB) * HH + j]) + bf2f(hlo[(b + BB) * HH + j]);
        s += fabsf(ha - hb);
    }
    #pragma unroll
    for (int off = 32; off > 0; off >>= 1) s += __shfl_down(s, off);
    if (lane == 0) out[b] = expf(-s);
}

// ---------------------------------------------------------------------------
extern "C" void kernel_launch(void* const* d_in, const int* in_sizes, int n_in,
                              void* d_out, int out_size, void* d_ws, size_t ws_size,
                              hipStream_t stream)
{
    const int*   s1  = (const int*)d_in[0];
    const int*   s2  = (const int*)d_in[1];
    const float* emb = (const float*)d_in[2];
    const float* Wih = (const float*)d_in[3];
    const float* Whh = (const float*)d_in[4];
    const float* bih = (const float*)d_in[5];
    const float* bhh = (const float*)d_in[6];
    const float* h0a = (const float*)d_in[7];
    const float* c0a = (const float*)d_in[8];
    const float* h0b = (const float*)d_in[9];
    const float* c0b = (const float*)d_in[10];
    float* out = (float*)d_out;

    char* ws = (char*)d_ws;
    unsigned short* Wcat = (unsigned short*)ws;                  // 2048*1856*2 = 7,602,176
    size_t off = (size_t)G4 * KTOT * 2;
    float* bias = (float*)(ws + off);            off += (size_t)G4 * 4;          // 8 KB
    unsigned short* hhi = (unsigned short*)(ws + off); off += 2 * (size_t)BT * HH * 2; // ping-pong
    unsigned short* hlo = (unsigned short*)(ws + off); off += 2 * (size_t)BT * HH * 2;
    float* cbuf = (float*)(ws + off);            off += 2 * (size_t)BT * HH * 4;
    // total ~11.8 MB of workspace

    prep_w<<<G4, 256, 0, stream>>>(Wih, Whh, bih, bhh, Wcat, bias);
    prep_h<<<BT, 256, 0, stream>>>(h0a, c0a, h0b, c0b, hhi, hlo, cbuf);

    for (int t = 0; t < TT; ++t) {
        int pi = t & 1, po = pi ^ 1;
        lstm_step<<<dim3(8, 32), 256, 0, stream>>>(
            s1, s2, emb, Wcat, bias,
            hhi + (size_t)pi * BT * HH, hlo + (size_t)pi * BT * HH,
            cbuf + (size_t)pi * BT * HH,
            hhi + (size_t)po * BT * HH, hlo + (size_t)po * BT * HH,
            cbuf + (size_t)po * BT * HH,
            t);
    }
    finalize<<<BB, 64, 0, stream>>>(hhi, hlo, out);
}

// Round 3
// 837.239 us; speedup vs baseline: 1.9151x; 1.9151x over previous
//
#include <hip/hip_runtime.h>
#include <hip/hip_bf16.h>
#include <math.h>

// Problem constants
#define TT 64
#define BB 256      // per-sequence batch
#define BT 512      // total batch (both sequences)
#define DD 300      // embedding dim
#define HH 512      // hidden
#define G4 2048     // 4*H
#define KX 320      // padded x-region of concat-K
#define KTOT 1856   // 320 + 3*512  (x | h_hi | h_lo | h_hi)
#define KC 64       // K chunk per LDS stage
#define NCH 29      // KTOT / KC

typedef __attribute__((ext_vector_type(8))) short short8v;
typedef __attribute__((ext_vector_type(4))) float f32x4;

__device__ __forceinline__ unsigned short f2bf(float f) {
    union { float f; unsigned int u; } v; v.f = f;
    unsigned int u = v.u;
    u += 0x7fffu + ((u >> 16) & 1u);   // round-to-nearest-even
    return (unsigned short)(u >> 16);
}
__device__ __forceinline__ float bf2f(unsigned short s) {
    union { unsigned int u; float f; } v; v.u = ((unsigned int)s) << 16;
    return v.f;
}
__device__ __forceinline__ float sigm(float x) { return 1.0f / (1.0f + __expf(-x)); }
__device__ __forceinline__ float tanh_f(float x) {
    float ax = fabsf(x);
    if (ax > 15.0f) return (x > 0.0f) ? 1.0f : -1.0f;
    float e = __expf(2.0f * ax);
    float t = 1.0f - 2.0f / (e + 1.0f);
    return (x >= 0.0f) ? t : -t;
}

// ---------------------------------------------------------------------------
// Prep: build Wcat bf16 [2048][1856] = [Wih|pad | Whh_hi | Whh_hi | Whh_lo],
// and bias = b_ih + b_hh.
__global__ __launch_bounds__(256) void prep_w(const float* __restrict__ Wih,
                                              const float* __restrict__ Whh,
                                              const float* __restrict__ bih,
                                              const float* __restrict__ bhh,
                                              unsigned short* __restrict__ Wcat,
                                              float* __restrict__ bias)
{
    const int row = blockIdx.x; // 0..2047
    for (int k = threadIdx.x; k < KTOT; k += 256) {
        unsigned short v;
        if (k < DD)                 v = f2bf(Wih[row * DD + k]);
        else if (k < KX)            v = 0;
        else if (k < KX + HH)       v = f2bf(Whh[row * HH + (k - KX)]);
        else if (k < KX + 2 * HH)   v = f2bf(Whh[row * HH + (k - KX - HH)]);
        else {
            float f = Whh[row * HH + (k - KX - 2 * HH)];
            unsigned short hi = f2bf(f);
            v = f2bf(f - bf2f(hi));
        }
        Wcat[(size_t)row * KTOT + k] = v;
    }
    if (threadIdx.x == 0) bias[row] = bih[row] + bhh[row];
}

// Prep: initial h (hi/lo bf16) and c for both sequences stacked.
__global__ __launch_bounds__(256) void prep_h(const float* __restrict__ h0a,
                                              const float* __restrict__ c0a,
                                              const float* __restrict__ h0b,
                                              const float* __restrict__ c0b,
                                              unsigned short* __restrict__ hhi,
                                              unsigned short* __restrict__ hlo,
                                              float* __restrict__ c)
{
    const int b = blockIdx.x; // 0..511
    for (int j = threadIdx.x; j < HH; j += 256) {
        float hv = (b < BB) ? h0a[b * HH + j] : h0b[(b - BB) * HH + j];
        float cv = (b < BB) ? c0a[b * HH + j] : c0b[(b - BB) * HH + j];
        unsigned short hi = f2bf(hv);
        hhi[b * HH + j] = hi;
        hlo[b * HH + j] = f2bf(hv - bf2f(hi));
        c[b * HH + j] = cv;
    }
}

// Pre-gather embeddings to bf16: Xbf[t][b][0..KX) (zero-padded past DD).
__global__ __launch_bounds__(256) void gather_x(const int* __restrict__ s1,
                                                const int* __restrict__ s2,
                                                const float* __restrict__ emb,
                                                unsigned short* __restrict__ Xbf)
{
    const int idx = blockIdx.x * 256 + threadIdx.x;   // TT*BT*40 threads
    const int row = idx / 40;          // t*512 + b
    const int seg = idx - row * 40;    // 8-elem segment within 320
    const int t = row >> 9;
    const int b = row & 511;
    const int tok = (b < BB) ? s1[t * BB + b] : s2[t * BB + (b - BB)];
    const int k = seg * 8;
    short8v v;
    if (k + 8 <= DD) {
        const float* e0 = emb + (size_t)tok * DD + k;
        float4 va = *(const float4*)e0;
        float4 vb = *(const float4*)(e0 + 4);
        v[0] = (short)f2bf(va.x); v[1] = (short)f2bf(va.y);
        v[2] = (short)f2bf(va.z); v[3] = (short)f2bf(va.w);
        v[4] = (short)f2bf(vb.x); v[5] = (short)f2bf(vb.y);
        v[6] = (short)f2bf(vb.z); v[7] = (short)f2bf(vb.w);
    } else {
        #pragma unroll
        for (int e = 0; e < 8; ++e) {
            int c = k + e;
            v[e] = (c < DD) ? (short)f2bf(emb[(size_t)tok * DD + c]) : (short)0;
        }
    }
    *(short8v*)&Xbf[(size_t)row * KX + k] = v;
}

// ---------------------------------------------------------------------------
// One LSTM timestep for all 512 batch rows. Tile 64 batch x 64 gate-cols
// (16 j x 4 gates). Grid 256 blocks, XCD-partitioned j-space so each XCD's
// L2 keeps its W-slice + A (~2.9 MB). Register-staged (global->VGPR early,
// ds_write after barrier), XOR-swizzled LDS (bank-conflict-free b128 R/W).
__global__ __launch_bounds__(256) void lstm_step(
    const unsigned short* __restrict__ Xbf,
    const unsigned short* __restrict__ Wcat,
    const float* __restrict__ bias,
    const unsigned short* __restrict__ hhi_in,
    const unsigned short* __restrict__ hlo_in,
    const float* __restrict__ c_in,
    unsigned short* __restrict__ hhi_out,
    unsigned short* __restrict__ hlo_out,
    float* __restrict__ c_out,
    int t)
{
    __shared__ __align__(16) unsigned short As[64 * 64];  // 8 KB
    __shared__ __align__(16) unsigned short Bs[64 * 64];  // 8 KB
    __shared__ __align__(16) float gbuf[64 * 65];          // 16.6 KB

    const int tid = threadIdx.x;
    const int bid = blockIdx.x;

    // XCD-aware decode: bid%8 = XCD (default round-robin). Each XCD owns a
    // contiguous jt range of 4 -> W slice 950 KB + A 1.9 MB fits its 4 MB L2.
    const int xcd   = bid & 7;
    const int local = bid >> 3;
    const int bx    = local & 7;              // batch block 0..7
    const int jt    = xcd * 4 + (local >> 3); // j tile 0..31
    const int jbase = jt * 16;                // hidden-column base

    const int lane = tid & 63;
    const int w = tid >> 6;
    const int wr = w >> 1, wc = w & 1;        // wave tile 32x32 within 64x64
    const int r16 = lane & 15;
    const int kg8 = lane >> 4;

    // staging decode: each wave stages 16 LDS rows (2 segments x 8 rows),
    // 8 lanes per row, 16B (one granule) per lane.
    const int sl8 = lane >> 3;                // row within 8-row segment
    const int gd  = lane & 7;                 // source granule within row

    f32x4 acc[2][2] = {};

    auto load_chunk = [&](int ch, short8v* va, short8v* vb) {
        const int k0 = ch * KC;
        const unsigned short* abase; int astride;
        if (k0 < KX) {
            abase = Xbf + ((size_t)t * BT + bx * 64) * KX + k0; astride = KX;
        } else if (k0 < KX + HH) {
            abase = hhi_in + (size_t)(bx * 64) * HH + (k0 - KX); astride = HH;
        } else if (k0 < KX + 2 * HH) {
            abase = hlo_in + (size_t)(bx * 64) * HH + (k0 - KX - HH); astride = HH;
        } else {
            abase = hhi_in + (size_t)(bx * 64) * HH + (k0 - KX - 2 * HH); astride = HH;
        }
        #pragma unroll
        for (int s = 0; s < 2; ++s) {
            const int r = w * 16 + s * 8 + sl8;               // LDS row 0..63
            va[s] = *(const short8v*)(abase + (size_t)r * astride + gd * 8);
            const int wrow = (r >> 4) * HH + jbase + (r & 15); // gate row
            vb[s] = *(const short8v*)(Wcat + (size_t)wrow * KTOT + k0 + gd * 8);
        }
    };
    auto write_chunk = [&](const short8v* va, const short8v* vb) {
        #pragma unroll
        for (int s = 0; s < 2; ++s) {
            const int r = w * 16 + s * 8 + sl8;
            const int g = (gd ^ sl8) << 3;    // XOR-swizzle (r&7 == sl8)
            *(short8v*)&As[r * 64 + g] = va[s];
            *(short8v*)&Bs[r * 64 + g] = vb[s];
        }
    };
    // swizzled LDS fragment address (in shorts)
    auto lidx = [&](int r, int ko) { return r * 64 + ((((ko) >> 3) ^ (r & 7)) << 3); };

    short8v va[2], vb[2], na[2], nb[2];
    load_chunk(0, va, vb);

    for (int ch = 0; ch < NCH; ++ch) {
        write_chunk(va, vb);
        if (ch + 1 < NCH) load_chunk(ch + 1, na, nb);  // hidden under MFMA phase
        __syncthreads();   // staged chunk visible
        #pragma unroll
        for (int ks = 0; ks < KC; ks += 32) {
            const int ko = ks + kg8 * 8;
            short8v a0 = *(const short8v*)&As[lidx(32 * wr + r16,      ko)];
            short8v a1 = *(const short8v*)&As[lidx(32 * wr + 16 + r16, ko)];
            short8v b0 = *(const short8v*)&Bs[lidx(32 * wc + r16,      ko)];
            short8v b1 = *(const short8v*)&Bs[lidx(32 * wc + 16 + r16, ko)];
            acc[0][0] = __builtin_amdgcn_mfma_f32_16x16x32_bf16(a0, b0, acc[0][0], 0, 0, 0);
            acc[0][1] = __builtin_amdgcn_mfma_f32_16x16x32_bf16(a0, b1, acc[0][1], 0, 0, 0);
            acc[1][0] = __builtin_amdgcn_mfma_f32_16x16x32_bf16(a1, b0, acc[1][0], 0, 0, 0);
            acc[1][1] = __builtin_amdgcn_mfma_f32_16x16x32_bf16(a1, b1, acc[1][1], 0, 0, 0);
        }
        __syncthreads();   // all reads done -> next iteration may overwrite
        #pragma unroll
        for (int s = 0; s < 2; ++s) { va[s] = na[s]; vb[s] = nb[s]; }
    }

    // exchange gates through LDS so each thread gets (i,f,g,o) for its (b,j)
    #pragma unroll
    for (int i = 0; i < 2; ++i)
        #pragma unroll
        for (int j = 0; j < 2; ++j)
            #pragma unroll
            for (int r = 0; r < 4; ++r) {
                int grow = (2 * wr + i) * 16 + kg8 * 4 + r; // C/D: row=(lane>>4)*4+reg
                int gcol = (2 * wc + j) * 16 + r16;         //      col=lane&15
                gbuf[grow * 65 + gcol] = acc[i][j][r];
            }
    __syncthreads();

    #pragma unroll
    for (int u = 0; u < 4; ++u) {
        int pair = tid + 256 * u;     // 1024 (b,j) pairs
        int row = pair >> 4;
        int jj = pair & 15;
        int batch = bx * 64 + row;
        int j = jbase + jj;
        float gi = gbuf[row * 65 + jj]      + bias[j];
        float gf = gbuf[row * 65 + 16 + jj] + bias[HH + j];
        float gg = gbuf[row * 65 + 32 + jj] + bias[2 * HH + j];
        float go = gbuf[row * 65 + 48 + jj] + bias[3 * HH + j];
        float cp = c_in[batch * HH + j];
        float cn = sigm(gf) * cp + sigm(gi) * tanh_f(gg);
        float hn = sigm(go) * tanh_f(cn);
        c_out[batch * HH + j] = cn;
        unsigned short hi = f2bf(hn);
        hhi_out[batch * HH + j] = hi;
        hlo_out[batch * HH + j] = f2bf(hn - bf2f(hi));
    }
}

// ---------------------------------------------------------------------------
__global__ __launch_bounds__(64) void finalize(const unsigned short* __restrict__ hhi,
                                               const unsigned short* __restrict__ hlo,
                                               float* __restrict__ out)
{
    const int b = blockIdx.x;       // 0..255
    const int lane = threadIdx.x;   // 64
    float s = 0.0f;
    for (int j = lane; j < HH; j += 64) {
        float ha = bf2f(hhi[b * HH + j]) + bf2f(hlo[b * HH + j]);
        float hb = bf2f(hhi[(b + BB) * HH + j]) + bf2f(hlo[(b + BB) * HH + j]);
        s += fabsf(ha - hb);
    }
    #pragma unroll
    for (int off = 32; off > 0; off >>= 1) s += __shfl_down(s, off);
    if (lane == 0) out[b] = expf(-s);
}

// ---------------------------------------------------------------------------
extern "C" void kernel_launch(void* const* d_in, const int* in_sizes, int n_in,
                              void* d_out, int out_size, void* d_ws, size_t ws_size,
                              hipStream_t stream)
{
    const int*   s1  = (const int*)d_in[0];
    const int*   s2  = (const int*)d_in[1];
    const float* emb = (const float*)d_in[2];
    const float* Wih = (const float*)d_in[3];
    const float* Whh = (const float*)d_in[4];
    const float* bih = (const float*)d_in[5];
    const float* bhh = (const float*)d_in[6];
    const float* h0a = (const float*)d_in[7];
    const float* c0a = (const float*)d_in[8];
    const float* h0b = (const float*)d_in[9];
    const float* c0b = (const float*)d_in[10];
    float* out = (float*)d_out;

    char* ws = (char*)d_ws;
    unsigned short* Wcat = (unsigned short*)ws;                       // 7,602,176 B
    size_t off = (size_t)G4 * KTOT * 2;
    float* bias = (float*)(ws + off);                  off += (size_t)G4 * 4;
    unsigned short* hhi = (unsigned short*)(ws + off); off += 2 * (size_t)BT * HH * 2;
    unsigned short* hlo = (unsigned short*)(ws + off); off += 2 * (size_t)BT * HH * 2;
    float* cbuf = (float*)(ws + off);                  off += 2 * (size_t)BT * HH * 4;
    unsigned short* Xbf = (unsigned short*)(ws + off); off += (size_t)TT * BT * KX * 2;
    // total ~33 MB of workspace (ws is 256 MiB)

    prep_w<<<G4, 256, 0, stream>>>(Wih, Whh, bih, bhh, Wcat, bias);
    prep_h<<<BT, 256, 0, stream>>>(h0a, c0a, h0b, c0b, hhi, hlo, cbuf);
    gather_x<<<(TT * BT * 40) / 256, 256, 0, stream>>>(s1, s2, emb, Xbf);

    for (int t = 0; t < TT; ++t) {
        int pi = t & 1, po = pi ^ 1;
        lstm_step<<<256, 256, 0, stream>>>(
            Xbf, Wcat, bias,
            hhi + (size_t)pi * BT * HH, hlo + (size_t)pi * BT * HH,
            cbuf + (size_t)pi * BT * HH,
            hhi + (size_t)po * BT * HH, hlo + (size_t)po * BT * HH,
            cbuf + (size_t)po * BT * HH,
            t);
    }
    finalize<<<BB, 64, 0, stream>>>(hhi, hlo, out);
}

// Round 4
// 757.134 us; speedup vs baseline: 2.1178x; 1.1058x over previous
//
#include <hip/hip_runtime.h>
#include <hip/hip_bf16.h>
#include <math.h>

// Problem constants
#define TT 64
#define BB 256      // per-sequence batch
#define BT 512      // total batch (both sequences)
#define DD 300      // embedding dim
#define HH 512      // hidden
#define G4 2048     // 4*H
#define KX 320      // padded x-region K
#define KH 1536     // h-part K: [hhi | hlo | hhi]
#define KC 64       // K chunk per LDS stage
#define NCHX 5      // KX / KC
#define NCHH 24     // KH / KC

typedef __attribute__((ext_vector_type(8))) short short8v;
typedef __attribute__((ext_vector_type(4))) float f32x4;
typedef __attribute__((ext_vector_type(4))) unsigned short ushort4v;

__device__ __forceinline__ unsigned short f2bf(float f) {
    union { float f; unsigned int u; } v; v.f = f;
    unsigned int u = v.u;
    u += 0x7fffu + ((u >> 16) & 1u);   // round-to-nearest-even
    return (unsigned short)(u >> 16);
}
__device__ __forceinline__ float bf2f(unsigned short s) {
    union { unsigned int u; float f; } v; v.u = ((unsigned int)s) << 16;
    return v.f;
}
__device__ __forceinline__ float sigm(float x) { return 1.0f / (1.0f + __expf(-x)); }
__device__ __forceinline__ float tanh_f(float x) {
    float ax = fabsf(x);
    if (ax > 15.0f) return (x > 0.0f) ? 1.0f : -1.0f;
    float e = __expf(2.0f * ax);
    float t = 1.0f - 2.0f / (e + 1.0f);
    return (x >= 0.0f) ? t : -t;
}

// ---------------------------------------------------------------------------
// Prep: permuted weights.
//  WcatP[g'][KH]: g' = jt*64 + grp*16 + jj  <->  gate g = grp*512 + jt*16 + jj
//    K layout: [0,512)=Whh_hi, [512,1024)=Whh_hi, [1024,1536)=Whh_lo
//    (pairs with A = [hhi | hlo | hhi]: hi*Whi + lo*Whi + hi*Wlo)
//  WihP[g'][KX]: bf16 W_ih rows (zero-padded 300..319)
//  biasP[jt*64 + jj*4 + grp] = b_ih[g] + b_hh[g]   (epilogue dwordx4 layout)
__global__ __launch_bounds__(256) void prep_w(const float* __restrict__ Wih,
                                              const float* __restrict__ Whh,
                                              const float* __restrict__ bih,
                                              const float* __restrict__ bhh,
                                              unsigned short* __restrict__ WcatP,
                                              unsigned short* __restrict__ WihP,
                                              float* __restrict__ biasP)
{
    const int gp = blockIdx.x;            // g' 0..2047
    const int jt = gp >> 6, r = gp & 63;
    const int grp = r >> 4, jj = r & 15;
    const int g = grp * 512 + jt * 16 + jj;

    for (int k = threadIdx.x; k < KH; k += 256) {
        unsigned short v;
        if (k < 2 * HH) {
            v = f2bf(Whh[(size_t)g * HH + (k & (HH - 1))]);     // hi (both regions)
        } else {
            float f = Whh[(size_t)g * HH + (k - 2 * HH)];
            unsigned short hi = f2bf(f);
            v = f2bf(f - bf2f(hi));                              // lo
        }
        WcatP[(size_t)gp * KH + k] = v;
    }
    for (int k = threadIdx.x; k < KX; k += 256)
        WihP[(size_t)gp * KX + k] = (k < DD) ? f2bf(Wih[(size_t)g * DD + k])
                                             : (unsigned short)0;
    if (threadIdx.x == 0) biasP[jt * 64 + jj * 4 + grp] = bih[g] + bhh[g];
}

// Prep: initial h (hi/lo bf16) and c for both sequences stacked.
__global__ __launch_bounds__(256) void prep_h(const float* __restrict__ h0a,
                                              const float* __restrict__ c0a,
                                              const float* __restrict__ h0b,
                                              const float* __restrict__ c0b,
                                              unsigned short* __restrict__ hhi,
                                              unsigned short* __restrict__ hlo,
                                              float* __restrict__ c)
{
    const int b = blockIdx.x; // 0..511
    for (int j = threadIdx.x; j < HH; j += 256) {
        float hv = (b < BB) ? h0a[b * HH + j] : h0b[(b - BB) * HH + j];
        float cv = (b < BB) ? c0a[b * HH + j] : c0b[(b - BB) * HH + j];
        unsigned short hi = f2bf(hv);
        hhi[b * HH + j] = hi;
        hlo[b * HH + j] = f2bf(hv - bf2f(hi));
        c[b * HH + j] = cv;
    }
}

// Pre-gather embeddings to bf16: Xbf[t*512+b][0..KX) (zero-padded past DD).
__global__ __launch_bounds__(256) void gather_x(const int* __restrict__ s1,
                                                const int* __restrict__ s2,
                                                const float* __restrict__ emb,
                                                unsigned short* __restrict__ Xbf)
{
    const int idx = blockIdx.x * 256 + threadIdx.x;   // TT*BT*40 threads
    const int row = idx / 40;          // t*512 + b
    const int seg = idx - row * 40;    // 8-elem segment within 320
    const int t = row >> 9;
    const int b = row & 511;
    const int tok = (b < BB) ? s1[t * BB + b] : s2[t * BB + (b - BB)];
    const int k = seg * 8;
    short8v v;
    if (k + 8 <= DD) {
        const float* e0 = emb + (size_t)tok * DD + k;
        float4 va = *(const float4*)e0;
        float4 vb = *(const float4*)(e0 + 4);
        v[0] = (short)f2bf(va.x); v[1] = (short)f2bf(va.y);
        v[2] = (short)f2bf(va.z); v[3] = (short)f2bf(va.w);
        v[4] = (short)f2bf(vb.x); v[5] = (short)f2bf(vb.y);
        v[6] = (short)f2bf(vb.z); v[7] = (short)f2bf(vb.w);
    } else {
        #pragma unroll
        for (int e = 0; e < 8; ++e) {
            int c = k + e;
            v[e] = (c < DD) ? (short)f2bf(emb[(size_t)tok * DD + c]) : (short)0;
        }
    }
    *(short8v*)&Xbf[(size_t)row * KX + k] = v;
}

// ---------------------------------------------------------------------------
// xprojP[m][g''] = sum_k Xbf[m][k]*WihP[g'][k], m = t*512+b,
// stored bf16 in epilogue layout g'' = jt*64 + jj*4 + grp.
// Tile 64 m-rows x 64 g'-cols; grid 512*32; plenty of block TLP.
__global__ __launch_bounds__(256) void gemm_x(
    const unsigned short* __restrict__ Xbf,
    const unsigned short* __restrict__ WihP,
    unsigned short* __restrict__ xprojP)
{
    __shared__ __align__(16) unsigned short As[64 * 64];
    __shared__ __align__(16) unsigned short Bs[64 * 64];
    __shared__ __align__(16) float gbuf[64 * 65];

    const int tid = threadIdx.x;
    const int nblk = blockIdx.x & 31;      // g' tile
    const int mblk = blockIdx.x >> 5;      // row tile

    const int lane = tid & 63;
    const int w = tid >> 6;
    const int wr = w >> 1, wc = w & 1;
    const int r16 = lane & 15;
    const int kg8 = lane >> 4;
    const int sl8 = lane >> 3;
    const int gd  = lane & 7;

    f32x4 acc[2][2] = {};

    auto load_chunk = [&](int ch, short8v* va, short8v* vb) {
        const int k0 = ch * KC;
        #pragma unroll
        for (int s = 0; s < 2; ++s) {
            const int r = w * 16 + s * 8 + sl8;
            va[s] = *(const short8v*)(Xbf + (size_t)(mblk * 64 + r) * KX + k0 + gd * 8);
            vb[s] = *(const short8v*)(WihP + (size_t)(nblk * 64 + r) * KX + k0 + gd * 8);
        }
    };
    auto write_chunk = [&](const short8v* va, const short8v* vb) {
        #pragma unroll
        for (int s = 0; s < 2; ++s) {
            const int r = w * 16 + s * 8 + sl8;
            const int g = (gd ^ sl8) << 3;
            *(short8v*)&As[r * 64 + g] = va[s];
            *(short8v*)&Bs[r * 64 + g] = vb[s];
        }
    };
    auto lidx = [&](int r, int ko) { return r * 64 + ((((ko) >> 3) ^ (r & 7)) << 3); };

    short8v va[2], vb[2], na[2], nb[2];
    load_chunk(0, va, vb);
    for (int ch = 0; ch < NCHX; ++ch) {
        write_chunk(va, vb);
        if (ch + 1 < NCHX) load_chunk(ch + 1, na, nb);
        __syncthreads();
        #pragma unroll
        for (int ks = 0; ks < KC; ks += 32) {
            const int ko = ks + kg8 * 8;
            short8v a0 = *(const short8v*)&As[lidx(32 * wr + r16,      ko)];
            short8v a1 = *(const short8v*)&As[lidx(32 * wr + 16 + r16, ko)];
            short8v b0 = *(const short8v*)&Bs[lidx(32 * wc + r16,      ko)];
            short8v b1 = *(const short8v*)&Bs[lidx(32 * wc + 16 + r16, ko)];
            acc[0][0] = __builtin_amdgcn_mfma_f32_16x16x32_bf16(a0, b0, acc[0][0], 0, 0, 0);
            acc[0][1] = __builtin_amdgcn_mfma_f32_16x16x32_bf16(a0, b1, acc[0][1], 0, 0, 0);
            acc[1][0] = __builtin_amdgcn_mfma_f32_16x16x32_bf16(a1, b0, acc[1][0], 0, 0, 0);
            acc[1][1] = __builtin_amdgcn_mfma_f32_16x16x32_bf16(a1, b1, acc[1][1], 0, 0, 0);
        }
        __syncthreads();
        #pragma unroll
        for (int s = 0; s < 2; ++s) { va[s] = na[s]; vb[s] = nb[s]; }
    }

    #pragma unroll
    for (int i = 0; i < 2; ++i)
        #pragma unroll
        for (int j = 0; j < 2; ++j)
            #pragma unroll
            for (int r = 0; r < 4; ++r) {
                int grow = (2 * wr + i) * 16 + kg8 * 4 + r;
                int gcol = (2 * wc + j) * 16 + r16;
                gbuf[grow * 65 + gcol] = acc[i][j][r];
            }
    __syncthreads();

    const int jj = tid & 15;
    const int row0 = tid >> 4;
    #pragma unroll
    for (int u = 0; u < 4; ++u) {
        int row = row0 + 16 * u;
        size_t m = (size_t)(mblk * 64 + row);
        ushort4v o;
        o[0] = f2bf(gbuf[row * 65 +      jj]);
        o[1] = f2bf(gbuf[row * 65 + 16 + jj]);
        o[2] = f2bf(gbuf[row * 65 + 32 + jj]);
        o[3] = f2bf(gbuf[row * 65 + 48 + jj]);
        *(ushort4v*)&xprojP[m * G4 + nblk * 64 + jj * 4] = o;
    }
}

// ---------------------------------------------------------------------------
// One LSTM timestep, K = 1536 (h-part only), 24 chunks, single-barrier
// double-buffered pipeline. Tile 64 batch x 64 gate-cols, 256 blocks,
// XCD-partitioned jt space. Epilogue folds bias + precomputed x-proj.
__global__ __launch_bounds__(256) void lstm_step(
    const unsigned short* __restrict__ WcatP,
    const float* __restrict__ biasP,
    const unsigned short* __restrict__ xprojP,
    const unsigned short* __restrict__ hhi_in,
    const unsigned short* __restrict__ hlo_in,
    const float* __restrict__ c_in,
    unsigned short* __restrict__ hhi_out,
    unsigned short* __restrict__ hlo_out,
    float* __restrict__ c_out,
    int t)
{
    __shared__ __align__(16) unsigned short As0[64 * 64], As1[64 * 64];
    __shared__ __align__(16) unsigned short Bs0[64 * 64], Bs1[64 * 64];
    __shared__ __align__(16) float gbuf[64 * 65];

    const int tid = threadIdx.x;
    const int bid = blockIdx.x;

    // XCD-aware decode: each XCD owns 4 contiguous jt tiles.
    const int xcd   = bid & 7;
    const int local = bid >> 3;
    const int bx    = local & 7;
    const int jt    = xcd * 4 + (local >> 3);

    const int lane = tid & 63;
    const int w = tid >> 6;
    const int wr = w >> 1, wc = w & 1;
    const int r16 = lane & 15;
    const int kg8 = lane >> 4;
    const int sl8 = lane >> 3;
    const int gd  = lane & 7;

    f32x4 acc[2][2] = {};

    auto load_chunk = [&](int ch, short8v* va, short8v* vb) {
        const int k0 = ch * KC;
        const unsigned short* abase;
        if (k0 < HH)            abase = hhi_in + (size_t)(bx * 64) * HH + k0;
        else if (k0 < 2 * HH)   abase = hlo_in + (size_t)(bx * 64) * HH + (k0 - HH);
        else                    abase = hhi_in + (size_t)(bx * 64) * HH + (k0 - 2 * HH);
        #pragma unroll
        for (int s = 0; s < 2; ++s) {
            const int r = w * 16 + s * 8 + sl8;
            va[s] = *(const short8v*)(abase + (size_t)r * HH + gd * 8);
            vb[s] = *(const short8v*)(WcatP + (size_t)(jt * 64 + r) * KH + k0 + gd * 8);
        }
    };
    auto write_chunk = [&](unsigned short* A, unsigned short* B,
                           const short8v* va, const short8v* vb) {
        #pragma unroll
        for (int s = 0; s < 2; ++s) {
            const int r = w * 16 + s * 8 + sl8;
            const int g = (gd ^ sl8) << 3;     // r&7 == sl8
            *(short8v*)&A[r * 64 + g] = va[s];
            *(short8v*)&B[r * 64 + g] = vb[s];
        }
    };
    auto lidx = [&](int r, int ko) { return r * 64 + ((((ko) >> 3) ^ (r & 7)) << 3); };
    auto compute = [&](const unsigned short* A, const unsigned short* B) {
        #pragma unroll
        for (int ks = 0; ks < KC; ks += 32) {
            const int ko = ks + kg8 * 8;
            short8v a0 = *(const short8v*)&A[lidx(32 * wr + r16,      ko)];
            short8v a1 = *(const short8v*)&A[lidx(32 * wr + 16 + r16, ko)];
            short8v b0 = *(const short8v*)&B[lidx(32 * wc + r16,      ko)];
            short8v b1 = *(const short8v*)&B[lidx(32 * wc + 16 + r16, ko)];
            acc[0][0] = __builtin_amdgcn_mfma_f32_16x16x32_bf16(a0, b0, acc[0][0], 0, 0, 0);
            acc[0][1] = __builtin_amdgcn_mfma_f32_16x16x32_bf16(a0, b1, acc[0][1], 0, 0, 0);
            acc[1][0] = __builtin_amdgcn_mfma_f32_16x16x32_bf16(a1, b0, acc[1][0], 0, 0, 0);
            acc[1][1] = __builtin_amdgcn_mfma_f32_16x16x32_bf16(a1, b1, acc[1][1], 0, 0, 0);
        }
    };

    short8v ra[2], rb[2], sa[2], sb[2];
    load_chunk(0, ra, rb);
    load_chunk(1, sa, sb);

    // epilogue prefetch (issued after staging loads so they don't gate them)
    const int jj = tid & 15;
    const int row0 = tid >> 4;
    f32x4 bp = *(const f32x4*)&biasP[jt * 64 + jj * 4];
    ushort4v xp[4]; float cp[4];
    #pragma unroll
    for (int u = 0; u < 4; ++u) {
        int batch = bx * 64 + row0 + 16 * u;
        xp[u] = *(const ushort4v*)&xprojP[((size_t)t * BT + batch) * G4 + jt * 64 + jj * 4];
        cp[u] = c_in[batch * HH + jt * 16 + jj];
    }

    write_chunk(As0, Bs0, ra, rb);
    __syncthreads();

    for (int ch = 0; ch < NCHH; ch += 2) {
        if (ch + 2 < NCHH) load_chunk(ch + 2, ra, rb);
        write_chunk(As1, Bs1, sa, sb);       // chunk ch+1 (always valid: NCHH even)
        compute(As0, Bs0);                    // chunk ch
        __syncthreads();
        if (ch + 3 < NCHH) load_chunk(ch + 3, sa, sb);
        if (ch + 2 < NCHH) write_chunk(As0, Bs0, ra, rb);
        compute(As1, Bs1);                    // chunk ch+1
        __syncthreads();
    }

    // exchange gates through LDS so each thread gets (i,f,g,o) for its (b,j)
    #pragma unroll
    for (int i = 0; i < 2; ++i)
        #pragma unroll
        for (int j2 = 0; j2 < 2; ++j2)
            #pragma unroll
            for (int r = 0; r < 4; ++r) {
                int grow = (2 * wr + i) * 16 + kg8 * 4 + r;
                int gcol = (2 * wc + j2) * 16 + r16;
                gbuf[grow * 65 + gcol] = acc[i][j2][r];
            }
    __syncthreads();

    #pragma unroll
    for (int u = 0; u < 4; ++u) {
        int row = row0 + 16 * u;
        int batch = bx * 64 + row;
        int j = jt * 16 + jj;
        float gi = gbuf[row * 65 +      jj] + bp[0] + bf2f(xp[u][0]);
        float gf = gbuf[row * 65 + 16 + jj] + bp[1] + bf2f(xp[u][1]);
        float gg = gbuf[row * 65 + 32 + jj] + bp[2] + bf2f(xp[u][2]);
        float go = gbuf[row * 65 + 48 + jj] + bp[3] + bf2f(xp[u][3]);
        float cn = sigm(gf) * cp[u] + sigm(gi) * tanh_f(gg);
        float hn = sigm(go) * tanh_f(cn);
        c_out[batch * HH + j] = cn;
        unsigned short hi = f2bf(hn);
        hhi_out[batch * HH + j] = hi;
        hlo_out[batch * HH + j] = f2bf(hn - bf2f(hi));
    }
}

// ---------------------------------------------------------------------------
__global__ __launch_bounds__(64) void finalize(const unsigned short* __restrict__ hhi,
                                               const unsigned short* __restrict__ hlo,
                                               float* __restrict__ out)
{
    const int b = blockIdx.x;       // 0..255
    const int lane = threadIdx.x;   // 64
    float s = 0.0f;
    for (int j = lane; j < HH; j += 64) {
        float ha = bf2f(hhi[b * HH + j]) + bf2f(hlo[b * HH + j]);
        float hb = bf2f(hhi[(b + BB) * HH + j]) + bf2f(hlo[(b + BB) * HH + j]);
        s += fabsf(ha - hb);
    }
    #pragma unroll
    for (int off = 32; off > 0; off >>= 1) s += __shfl_down(s, off);
    if (lane == 0) out[b] = expf(-s);
}

// ---------------------------------------------------------------------------
extern "C" void kernel_launch(void* const* d_in, const int* in_sizes, int n_in,
                              void* d_out, int out_size, void* d_ws, size_t ws_size,
                              hipStream_t stream)
{
    const int*   s1  = (const int*)d_in[0];
    const int*   s2  = (const int*)d_in[1];
    const float* emb = (const float*)d_in[2];
    const float* Wih = (const float*)d_in[3];
    const float* Whh = (const float*)d_in[4];
    const float* bih = (const float*)d_in[5];
    const float* bhh = (const float*)d_in[6];
    const float* h0a = (const float*)d_in[7];
    const float* c0a = (const float*)d_in[8];
    const float* h0b = (const float*)d_in[9];
    const float* c0b = (const float*)d_in[10];
    float* out = (float*)d_out;

    char* ws = (char*)d_ws;
    size_t off = 0;
    unsigned short* WcatP = (unsigned short*)(ws + off); off += (size_t)G4 * KH * 2;   // 6.29 MB
    unsigned short* WihP  = (unsigned short*)(ws + off); off += (size_t)G4 * KX * 2;   // 1.31 MB
    float* biasP          = (float*)(ws + off);          off += (size_t)G4 * 4;        // 8 KB
    unsigned short* hhi   = (unsigned short*)(ws + off); off += 2 * (size_t)BT * HH * 2;
    unsigned short* hlo   = (unsigned short*)(ws + off); off += 2 * (size_t)BT * HH * 2;
    float* cbuf           = (float*)(ws + off);          off += 2 * (size_t)BT * HH * 4;
    unsigned short* Xbf   = (unsigned short*)(ws + off); off += (size_t)TT * BT * KX * 2; // 21 MB
    unsigned short* xprojP= (unsigned short*)(ws + off); off += (size_t)TT * BT * G4 * 2; // 134 MB
    // total ~167 MB of the 256 MiB workspace

    prep_w<<<G4, 256, 0, stream>>>(Wih, Whh, bih, bhh, WcatP, WihP, biasP);
    prep_h<<<BT, 256, 0, stream>>>(h0a, c0a, h0b, c0b, hhi, hlo, cbuf);
    gather_x<<<(TT * BT * 40) / 256, 256, 0, stream>>>(s1, s2, emb, Xbf);
    gemm_x<<<512 * 32, 256, 0, stream>>>(Xbf, WihP, xprojP);

    for (int t = 0; t < TT; ++t) {
        int pi = t & 1, po = pi ^ 1;
        lstm_step<<<256, 256, 0, stream>>>(
            WcatP, biasP, xprojP,
            hhi + (size_t)pi * BT * HH, hlo + (size_t)pi * BT * HH,
            cbuf + (size_t)pi * BT * HH,
            hhi + (size_t)po * BT * HH, hlo + (size_t)po * BT * HH,
            cbuf + (size_t)po * BT * HH,
            t);
    }
    finalize<<<BB, 64, 0, stream>>>(hhi, hlo, out);
}